// Round 4
// baseline (540.606 us; speedup 1.0000x reference)
//
#include <hip/hip_runtime.h>
#include <cstdint>
#include <cstddef>

// Problem constants: B=4, T=827, C=1024, NH=16, HS=64, SCALE=1/8
#define Tn  827
#define Cn  1024
#define BTn 3308      // B*T
#define TPn 832       // T padded to multiple of 32/64
#define YSZ 3387392   // B*T*C  (y output elements)

typedef unsigned short u16;
typedef unsigned short u16x4 __attribute__((ext_vector_type(4)));
typedef __bf16 bf16_t;
typedef bf16_t bf16x8 __attribute__((ext_vector_type(8)));
typedef float f32x4 __attribute__((ext_vector_type(4)));

__device__ inline u16 f32_to_bf16(float f) {
  union { float f; unsigned u; } v; v.f = f;
  unsigned u = v.u;
  u += 0x7fffu + ((u >> 16) & 1u);   // RNE
  return (u16)(u >> 16);
}

// ---------------------------------------------------------------------------
// f32 -> bf16 conversion for x, x_kv, Wq, Wk, Wv, Wp (one fused launch)
// ---------------------------------------------------------------------------
__global__ __launch_bounds__(256)
void cvt_all_k(const float* __restrict__ x, const float* __restrict__ xkv,
               const float* __restrict__ wq, const float* __restrict__ wk,
               const float* __restrict__ wv, const float* __restrict__ wp,
               u16* __restrict__ xb, u16* __restrict__ xkb,
               u16* __restrict__ wqb, u16* __restrict__ wkb,
               u16* __restrict__ wvb, u16* __restrict__ wpb)
{
  const long NX = 846848;   // YSZ/4
  const long NW = 262144;   // C*C/4
  long qidx = (long)blockIdx.x * 256 + threadIdx.x;
  const float* s; u16* d; long base;
  if (qidx < NX)            { s = x;   d = xb;  base = qidx; }
  else if (qidx < 2 * NX)   { s = xkv; d = xkb; base = qidx - NX; }
  else {
    long w = qidx - 2 * NX;
    int wi = (int)(w / NW);
    base = w - (long)wi * NW;
    if      (wi == 0) { s = wq; d = wqb; }
    else if (wi == 1) { s = wk; d = wkb; }
    else if (wi == 2) { s = wv; d = wvb; }
    else if (wi == 3) { s = wp; d = wpb; }
    else return;
  }
  const float4 v = *(const float4*)(s + base * 4);
  u16x4 o;
  o.x = f32_to_bf16(v.x); o.y = f32_to_bf16(v.y);
  o.z = f32_to_bf16(v.z); o.w = f32_to_bf16(v.w);
  *(u16x4*)(d + base * 4) = o;
}

// ---------------------------------------------------------------------------
// Pipelined bf16 MFMA GEMM: C = A(Mx1024) . B(Nx1024)^T, BM=128 BN=64 BK=64.
// Register-prefetch pipeline: global->VGPR loads for tile kt+1 issued before
// compute of tile kt; ds_write after compute (vmcnt wait lands post-compute,
// NOT at the barrier — the m97 drain is off the critical path).
// LDS rows padded to 72 elems (16B-aligned, 2-way bank alias = free).
// MODE 0: -> Cb bf16 +bias | MODE 3: -> Cf fp32 +bias
// MODE 4: KV split: col<1024 -> Cb(+bias), else -> Cb2(+bias2)
// ---------------------------------------------------------------------------
template<int MODE>
__global__ __launch_bounds__(256)
void pgemm_k(const u16* __restrict__ A, const u16* __restrict__ Bw,
             const float* __restrict__ bias, const float* __restrict__ bias2,
             float* __restrict__ Cf, u16* __restrict__ Cb, u16* __restrict__ Cb2,
             int M, int N)
{
  constexpr int BM = 128, BN = 64, BK = 64, STB = 144;  // STB = LDS row stride bytes (72 elems)
  __shared__ u16 As[2][BM * 72];
  __shared__ u16 Bs[2][BN * 72];

  const int tid  = threadIdx.x;
  const int lane = tid & 63;
  const int wave = tid >> 6;
  const int quad = lane >> 4, cl = lane & 15;
  const int wm = wave >> 1, wn = wave & 1;
  const int m0 = blockIdx.x * BM;
  const int n0 = blockIdx.y * BN;

  float4 av[4], bv[2];

  auto loadT = [&](int kt) {
    const int k0 = kt * BK;
    #pragma unroll
    for (int i = 0; i < 4; ++i) {
      const int c = tid + 256 * i;
      int gr = m0 + (c >> 3);
      if (gr >= M) gr = M - 1;                  // clamp: rows never stored
      av[i] = *(const float4*)(A + (size_t)gr * 1024 + k0 + (c & 7) * 8);
    }
    #pragma unroll
    for (int i = 0; i < 2; ++i) {
      const int c = tid + 256 * i;
      bv[i] = *(const float4*)(Bw + (size_t)(n0 + (c >> 3)) * 1024 + k0 + (c & 7) * 8);
    }
  };
  auto writeT = [&](int nb) {
    #pragma unroll
    for (int i = 0; i < 4; ++i) {
      const int c = tid + 256 * i;
      *(float4*)((char*)&As[nb][0] + (c >> 3) * STB + (c & 7) * 16) = av[i];
    }
    #pragma unroll
    for (int i = 0; i < 2; ++i) {
      const int c = tid + 256 * i;
      *(float4*)((char*)&Bs[nb][0] + (c >> 3) * STB + (c & 7) * 16) = bv[i];
    }
  };

  f32x4 acc[4][2];
  const f32x4 zero4 = {0.f, 0.f, 0.f, 0.f};
  #pragma unroll
  for (int i = 0; i < 4; ++i) { acc[i][0] = zero4; acc[i][1] = zero4; }

  loadT(0);
  writeT(0);
  __syncthreads();

  for (int kt = 0; kt < 16; ++kt) {
    const int cur = kt & 1;
    if (kt < 15) loadT(kt + 1);                 // in flight during compute
    #pragma unroll
    for (int ks = 0; ks < 2; ++ks) {
      bf16x8 af[4], bfr[2];
      #pragma unroll
      for (int i = 0; i < 4; ++i)
        af[i] = *(const bf16x8*)((const char*)&As[cur][0] +
                                 (wm * 64 + i * 16 + cl) * STB + ks * 64 + quad * 16);
      #pragma unroll
      for (int j = 0; j < 2; ++j)
        bfr[j] = *(const bf16x8*)((const char*)&Bs[cur][0] +
                                  (wn * 32 + j * 16 + cl) * STB + ks * 64 + quad * 16);
      #pragma unroll
      for (int i = 0; i < 4; ++i)
        #pragma unroll
        for (int j = 0; j < 2; ++j)
          acc[i][j] = __builtin_amdgcn_mfma_f32_16x16x32_bf16(af[i], bfr[j], acc[i][j], 0, 0, 0);
    }
    if (kt < 15) writeT(cur ^ 1);               // vmcnt wait here (post-compute)
    __syncthreads();                            // only lgkm drain needed
  }

  #pragma unroll
  for (int i = 0; i < 4; ++i) {
    #pragma unroll
    for (int j = 0; j < 2; ++j) {
      const int rb  = m0 + wm * 64 + i * 16 + quad * 4;
      const int col = n0 + wn * 32 + j * 16 + cl;
      #pragma unroll
      for (int r = 0; r < 4; ++r) {
        const int row = rb + r;
        if (row >= M) continue;
        const float v = acc[i][j][r];
        if constexpr (MODE == 0) {
          Cb[(size_t)row * 1024 + col] = f32_to_bf16(v + bias[col]);
        } else if constexpr (MODE == 4) {
          if (col < 1024) Cb[(size_t)row * 1024 + col] = f32_to_bf16(v + bias[col]);
          else            Cb2[(size_t)row * 1024 + col - 1024] = f32_to_bf16(v + bias2[col - 1024]);
        } else {
          Cf[(size_t)row * 1024 + col] = v + bias[col];
        }
      }
    }
  }
}

// ---------------------------------------------------------------------------
// V (B,T,C) bf16 -> Vt (B*NH, 64, TPn) bf16 (zero-padded k >= T)
// ---------------------------------------------------------------------------
__global__ __launch_bounds__(256)
void vtrans_k(const u16* __restrict__ V, u16* __restrict__ Vt)
{
  const int z = blockIdx.y;
  const int b = z >> 4, hh = z & 15;
  const int k0 = blockIdx.x * 64;
  const int tid = threadIdx.x;
  __shared__ u16 tile[64 * 65];
  #pragma unroll
  for (int rep = 0; rep < 16; ++rep) {
    const int idx = rep * 256 + tid;
    const int kl = idx >> 6, n = idx & 63;
    const int k = k0 + kl;
    u16 val = 0;
    if (k < Tn) val = V[((size_t)(b * Tn + k)) * Cn + hh * 64 + n];
    tile[n * 65 + kl] = val;
  }
  __syncthreads();
  #pragma unroll
  for (int rep = 0; rep < 16; ++rep) {
    const int idx = rep * 256 + tid;
    const int n = idx >> 6, kl = idx & 63;
    const int k = k0 + kl;
    if (k < TPn) Vt[((size_t)z * 64 + n) * TPn + k] = tile[n * 65 + kl];
  }
}

// ---------------------------------------------------------------------------
// b01/b02/b12 -> transposed copies bT[rg*4+b][256][256] with [i][j]=b[b][j][i]
// ---------------------------------------------------------------------------
__global__ __launch_bounds__(256)
void btrans_k(const float* __restrict__ b01, const float* __restrict__ b02,
              const float* __restrict__ b12, float* __restrict__ bT)
{
  const int mb = blockIdx.z;       // rg*4 + b
  const int rg = mb >> 2, bb = mb & 3;
  const float* src = (rg == 0 ? b01 : rg == 1 ? b02 : b12) + (size_t)bb * 65536;
  float* dst = bT + (size_t)mb * 65536;
  const int i0 = blockIdx.x * 64, j0 = blockIdx.y * 64;
  __shared__ float tile[64 * 65];
  const int tid = threadIdx.x;
  #pragma unroll
  for (int rep = 0; rep < 16; ++rep) {
    const int idx = rep * 256 + tid;
    const int jj = idx >> 6, ii = idx & 63;
    tile[ii * 65 + jj] = src[(size_t)(j0 + jj) * 256 + i0 + ii];
  }
  __syncthreads();
  #pragma unroll
  for (int rep = 0; rep < 16; ++rep) {
    const int idx = rep * 256 + tid;
    const int ii = idx >> 6, jj = idx & 63;
    dst[(size_t)(i0 + ii) * 256 + j0 + jj] = tile[ii * 65 + jj];
  }
}

// ---------------------------------------------------------------------------
// Regional score blocks: Sreg[z*3+rg][256][256] = Q.K^T*SCALE + h
// ---------------------------------------------------------------------------
__global__ __launch_bounds__(256)
void sreg_k(const u16* __restrict__ Qb, const u16* __restrict__ Kb,
            const float* __restrict__ hsrc, float* __restrict__ Sreg)
{
  const int zr = blockIdx.z;          // z*3+rg
  const int rg = zr % 3;
  const int z  = zr / 3;
  const int b = z >> 4, hh = z & 15;
  const int qoff = (rg == 0) ? 285 : 571;
  const int koff = (rg == 2) ? 286 : 0;
  const int m0 = blockIdx.x * 64;
  const int n0 = blockIdx.y * 64;

  const int tid = threadIdx.x;
  const int lane = tid & 63, wave = tid >> 6;
  const int quad = lane >> 4, cl = lane & 15;
  const int wm = wave >> 1, wn = wave & 1;

  __shared__ u16 As[2048], Bs[2048];

  const u16* Ab = Qb + ((size_t)(b * Tn + qoff + m0)) * Cn + hh * 64;
  const u16* Bb = Kb + ((size_t)(b * Tn + koff + n0)) * Cn + hh * 64;

  f32x4 acc[2][2];
  const f32x4 zero4 = {0.f, 0.f, 0.f, 0.f};
  acc[0][0] = zero4; acc[0][1] = zero4; acc[1][0] = zero4; acc[1][1] = zero4;

  #pragma unroll
  for (int kt = 0; kt < 2; ++kt) {
    const int k0 = kt * 32;
    __syncthreads();
    const int r = tid >> 2, ko = (tid & 3) << 3;
    __builtin_amdgcn_global_load_lds(
        (__attribute__((address_space(1))) void*)(Ab + (size_t)r * Cn + k0 + ko),
        (__attribute__((address_space(3))) void*)(&As[wave * 512]), 16, 0, 0);
    __builtin_amdgcn_global_load_lds(
        (__attribute__((address_space(1))) void*)(Bb + (size_t)r * Cn + k0 + ko),
        (__attribute__((address_space(3))) void*)(&Bs[wave * 512]), 16, 0, 0);
    __syncthreads();
    bf16x8 af[2], bfr[2];
    #pragma unroll
    for (int i = 0; i < 2; ++i)
      af[i] = *(const bf16x8*)(&As[(wm * 32 + i * 16 + cl) * 32 + quad * 8]);
    #pragma unroll
    for (int j = 0; j < 2; ++j)
      bfr[j] = *(const bf16x8*)(&Bs[(wn * 32 + j * 16 + cl) * 32 + quad * 8]);
    #pragma unroll
    for (int i = 0; i < 2; ++i)
      #pragma unroll
      for (int j = 0; j < 2; ++j)
        acc[i][j] = __builtin_amdgcn_mfma_f32_16x16x32_bf16(af[i], bfr[j], acc[i][j], 0, 0, 0);
  }

  float hvv[2][2][4];
  const size_t hb0 = (size_t)z * Tn * Tn;
  #pragma unroll
  for (int i = 0; i < 2; ++i)
    #pragma unroll
    for (int j = 0; j < 2; ++j)
      #pragma unroll
      for (int r = 0; r < 4; ++r) {
        const int row = m0 + wm * 32 + i * 16 + quad * 4 + r;
        const int col = n0 + wn * 32 + j * 16 + cl;
        hvv[i][j][r] = hsrc[hb0 + (size_t)(qoff + row) * Tn + koff + col];
      }
  float* outb = Sreg + ((size_t)zr << 16);
  #pragma unroll
  for (int i = 0; i < 2; ++i)
    #pragma unroll
    for (int j = 0; j < 2; ++j)
      #pragma unroll
      for (int r = 0; r < 4; ++r) {
        const int row = m0 + wm * 32 + i * 16 + quad * 4 + r;
        const int col = n0 + wn * 32 + j * 16 + cl;
        outb[(size_t)row * 256 + col] = acc[i][j][r] * 0.125f + hvv[i][j][r];
      }
}

// ---------------------------------------------------------------------------
// Regional softmax / stats / multiply / second softmax on Sreg. One wave/row.
// ---------------------------------------------------------------------------
__global__ __launch_bounds__(256)
void regional_k(float* __restrict__ Sreg, const float* __restrict__ f01,
                const float* __restrict__ f02, const float* __restrict__ f12,
                const float* __restrict__ bT,
                float* __restrict__ mmOut, float* __restrict__ amOut)
{
  const int tid  = threadIdx.x;
  const int lane = tid & 63;
  const int wrow = tid >> 6;
  const int row_id = blockIdx.x * 4 + wrow;      // 0 .. 49151
  const int region = row_id >> 14;
  const int rr = row_id & 16383;
  const int b  = rr >> 12;
  const int hh = (rr >> 8) & 15;
  const int i  = rr & 255;
  float* rp = Sreg + ((size_t)(((b * 16 + hh) * 3) + region) << 16) + (size_t)i * 256;

  const float* fp = (region == 0) ? f01 : (region == 1) ? f02 : f12;
  const float* bp = bT + ((size_t)(region * 4 + b) << 16);

  float v[4], fv[4], bv[4];
  #pragma unroll
  for (int t = 0; t < 4; ++t) {
    const int j = lane + 64 * t;
    v[t]  = rp[j];
    fv[t] = fp[((size_t)b * 256 + i) * 256 + j];
    bv[t] = bp[(size_t)i * 256 + j];
  }
  float mx = fmaxf(fmaxf(v[0], v[1]), fmaxf(v[2], v[3]));
  for (int m = 32; m > 0; m >>= 1) mx = fmaxf(mx, __shfl_xor(mx, m));
  float e[4], s = 0.f;
  #pragma unroll
  for (int t = 0; t < 4; ++t) { e[t] = __expf(v[t] - mx); s += e[t]; }
  for (int m = 32; m > 0; m >>= 1) s += __shfl_xor(s, m);
  const float inv = 1.f / s;
  float sm[4];
  #pragma unroll
  for (int t = 0; t < 4; ++t) sm[t] = e[t] * inv;

  if (region == 2) {
    float msum = 0.f, mcnt = 0.f, asum = 0.f;
    #pragma unroll
    for (int t = 0; t < 4; ++t) {
      const float mk = (fv[t] * bv[t] >= 0.1f) ? 1.f : 0.f;
      msum += sm[t] * mk; mcnt += mk; asum += sm[t];
    }
    for (int m = 32; m > 0; m >>= 1) {
      msum += __shfl_xor(msum, m);
      mcnt += __shfl_xor(mcnt, m);
      asum += __shfl_xor(asum, m);
    }
    if (lane == 0) {
      const int idx = (b * 16 + hh) * 256 + i;
      mmOut[idx] = msum / mcnt;
      amOut[idx] = asum * (1.f / 256.f);
    }
  }

  float mult[4];
  #pragma unroll
  for (int t = 0; t < 4; ++t) mult[t] = sm[t] * fv[t] * bv[t];

  if (region == 0) {
    #pragma unroll
    for (int t = 0; t < 4; ++t) rp[lane + 64 * t] = mult[t];
  } else {
    float mx2 = fmaxf(fmaxf(mult[0], mult[1]), fmaxf(mult[2], mult[3]));
    for (int m = 32; m > 0; m >>= 1) mx2 = fmaxf(mx2, __shfl_xor(mx2, m));
    float e2[4], s2 = 0.f;
    #pragma unroll
    for (int t = 0; t < 4; ++t) { e2[t] = __expf(mult[t] - mx2); s2 += e2[t]; }
    for (int m = 32; m > 0; m >>= 1) s2 += __shfl_xor(s2, m);
    const float inv2 = 1.f / s2;
    #pragma unroll
    for (int t = 0; t < 4; ++t) rp[lane + 64 * t] = e2[t] * inv2;
  }
}

// ---------------------------------------------------------------------------
// Fused flash attention (unchanged from R3): per 64-row q-tile, stream
// 64-col k-tiles; s = QK^T*SCALE + h (or Sreg overlay); causal online
// softmax; O += P.V; final O/l -> ya (B,T,C bf16).
// ---------------------------------------------------------------------------
__global__ __launch_bounds__(256)
void flash_k(const u16* __restrict__ Qb, const u16* __restrict__ Kb,
             const u16* __restrict__ Vt, const float* __restrict__ hsrc,
             const float* __restrict__ Sreg, u16* __restrict__ ya)
{
  const int bid = blockIdx.x;          // 0..831
  const int zlow = bid & 7;
  const int t = bid >> 3;              // 0..103
  const int qt = t % 13;
  const int zhigh = t / 13;
  const int z = zhigh * 8 + zlow;
  const int b = z >> 4, hh = z & 15;
  const int q0 = qt * 64;

  const int tid = threadIdx.x;
  const int lane = tid & 63;
  const int wave = tid >> 6;
  const int quad = lane >> 4;
  const int cl = lane & 15;

  __shared__ u16 Qs[2][2048];
  __shared__ u16 Ks[2][2048];
  __shared__ u16 Vs[2][2048];
  __shared__ u16 Ps[4][2][512];

  {
    const u16* src = Qb + ((size_t)(b * Tn + q0)) * Cn + hh * 64;
    const int r = tid >> 2;
    const int ko = (tid & 3) << 3;
    #pragma unroll
    for (int p = 0; p < 2; ++p)
      __builtin_amdgcn_global_load_lds(
          (__attribute__((address_space(1))) void*)(src + (size_t)r * Cn + p * 32 + ko),
          (__attribute__((address_space(3))) void*)(&Qs[p][wave * 512]), 16, 0, 0);
  }
  __syncthreads();

  bf16x8 qa[2];
  #pragma unroll
  for (int p = 0; p < 2; ++p)
    qa[p] = *(const bf16x8*)(&Qs[p][(wave * 16 + cl) * 32 + quad * 8]);

  f32x4 Oa[4];
  const f32x4 zero4 = {0.f, 0.f, 0.f, 0.f};
  Oa[0] = zero4; Oa[1] = zero4; Oa[2] = zero4; Oa[3] = zero4;
  float mrow[4] = {-3.0e38f, -3.0e38f, -3.0e38f, -3.0e38f};
  float lrow[4] = {0.f, 0.f, 0.f, 0.f};

  const size_t hbase = (size_t)z * Tn * Tn;
  const int qrow_base = q0 + wave * 16 + quad * 4;

  for (int kt = 0; kt <= qt; ++kt) {
    const int k0 = kt * 64;
    __syncthreads();
    {
      const u16* ksrc = Kb + ((size_t)(b * Tn + k0)) * Cn + hh * 64;
      const u16* vsrc = Vt + ((size_t)(z * 64)) * TPn + k0;
      const int r = tid >> 2;
      const int ko = (tid & 3) << 3;
      #pragma unroll
      for (int p = 0; p < 2; ++p) {
        __builtin_amdgcn_global_load_lds(
            (__attribute__((address_space(1))) void*)(ksrc + (size_t)r * Cn + p * 32 + ko),
            (__attribute__((address_space(3))) void*)(&Ks[p][wave * 512]), 16, 0, 0);
        __builtin_amdgcn_global_load_lds(
            (__attribute__((address_space(1))) void*)(vsrc + (size_t)r * TPn + p * 32 + ko),
            (__attribute__((address_space(3))) void*)(&Vs[p][wave * 512]), 16, 0, 0);
      }
    }
    float hv[4][4];
    unsigned rmask = 0;
    #pragma unroll
    for (int j = 0; j < 4; ++j) {
      const int kk = k0 + j * 16 + cl;
      #pragma unroll
      for (int r = 0; r < 4; ++r) {
        const int qq = qrow_base + r;
        const float* p = hsrc + hbase + (size_t)qq * Tn + kk;
        bool isreg = false;
        if (kk < 542) {
          if (qq >= 571 && qq < Tn) {
            if (kk < 256) {
              p = Sreg + (((size_t)(z * 3 + 1)) << 16) + (size_t)(qq - 571) * 256 + kk;
              isreg = true;
            } else if (kk >= 286) {
              p = Sreg + (((size_t)(z * 3 + 2)) << 16) + (size_t)(qq - 571) * 256 + (kk - 286);
              isreg = true;
            }
          } else if (qq >= 285 && qq < 541 && kk < 256) {
            p = Sreg + (((size_t)(z * 3 + 0)) << 16) + (size_t)(qq - 285) * 256 + kk;
            isreg = true;
          }
        }
        const bool valid = (kk <= qq) && (qq < Tn);
        hv[j][r] = valid ? *p : 0.f;
        if (isreg) rmask |= 1u << (j * 4 + r);
      }
    }
    __syncthreads();

    f32x4 sa[4];
    sa[0] = zero4; sa[1] = zero4; sa[2] = zero4; sa[3] = zero4;
    #pragma unroll
    for (int p = 0; p < 2; ++p) {
      #pragma unroll
      for (int n = 0; n < 4; ++n) {
        const bf16x8 kb = *(const bf16x8*)(&Ks[p][(n * 16 + cl) * 32 + quad * 8]);
        sa[n] = __builtin_amdgcn_mfma_f32_16x16x32_bf16(qa[p], kb, sa[n], 0, 0, 0);
      }
    }

    #pragma unroll
    for (int r = 0; r < 4; ++r) {
      const int qq = qrow_base + r;
      float sv[4];
      #pragma unroll
      for (int j = 0; j < 4; ++j) {
        const int kk = k0 + j * 16 + cl;
        const float vv = ((rmask >> (j * 4 + r)) & 1)
                             ? hv[j][r]
                             : sa[j][r] * 0.125f + hv[j][r];
        sv[j] = (kk <= qq && qq < Tn) ? vv : -3.0e38f;
      }
      float mx = fmaxf(fmaxf(sv[0], sv[1]), fmaxf(sv[2], sv[3]));
      mx = fmaxf(mx, __shfl_xor(mx, 1));
      mx = fmaxf(mx, __shfl_xor(mx, 2));
      mx = fmaxf(mx, __shfl_xor(mx, 4));
      mx = fmaxf(mx, __shfl_xor(mx, 8));
      const float mnew = fmaxf(mrow[r], mx);
      const float alpha = __expf(mrow[r] - mnew);
      mrow[r] = mnew;
      float ps[4], psum = 0.f;
      #pragma unroll
      for (int j = 0; j < 4; ++j) { ps[j] = __expf(sv[j] - mnew); psum += ps[j]; }
      psum += __shfl_xor(psum, 1);
      psum += __shfl_xor(psum, 2);
      psum += __shfl_xor(psum, 4);
      psum += __shfl_xor(psum, 8);
      lrow[r] = lrow[r] * alpha + psum;
      #pragma unroll
      for (int n = 0; n < 4; ++n) Oa[n][r] *= alpha;
      #pragma unroll
      for (int j = 0; j < 4; ++j)
        Ps[wave][j >> 1][(quad * 4 + r) * 32 + (j & 1) * 16 + cl] = f32_to_bf16(ps[j]);
    }

    #pragma unroll
    for (int p = 0; p < 2; ++p) {
      const bf16x8 pa = *(const bf16x8*)(&Ps[wave][p][cl * 32 + quad * 8]);
      #pragma unroll
      for (int n = 0; n < 4; ++n) {
        const bf16x8 vb = *(const bf16x8*)(&Vs[p][(n * 16 + cl) * 32 + quad * 8]);
        Oa[n] = __builtin_amdgcn_mfma_f32_16x16x32_bf16(pa, vb, Oa[n], 0, 0, 0);
      }
    }
  }

  #pragma unroll
  for (int r = 0; r < 4; ++r) {
    const int qq = qrow_base + r;
    if (qq >= Tn) continue;
    const float inv = 1.f / lrow[r];
    u16* op = ya + ((size_t)(b * Tn + qq)) * Cn + hh * 64;
    #pragma unroll
    for (int n = 0; n < 4; ++n)
      op[n * 16 + cl] = f32_to_bf16(Oa[n][r] * inv);
  }
}

// ---------------------------------------------------------------------------
// bi_epi_ratio[b,i] = sum_h(mask_mean) / sum_h(mean)
// ---------------------------------------------------------------------------
__global__ __launch_bounds__(256)
void ratio_k(const float* __restrict__ mm, const float* __restrict__ am,
             float* __restrict__ out)
{
  const int idx = blockIdx.x * 256 + threadIdx.x;   // 0..1023
  const int b = idx >> 8, i = idx & 255;
  float smm = 0.f, sam = 0.f;
  #pragma unroll
  for (int hh = 0; hh < 16; ++hh) {
    smm += mm[(b * 16 + hh) * 256 + i];
    sam += am[(b * 16 + hh) * 256 + i];
  }
  out[idx] = smm / sam;
}

// ---------------------------------------------------------------------------
extern "C" void kernel_launch(void* const* d_in, const int* in_sizes, int n_in,
                              void* d_out, int out_size, void* d_ws, size_t ws_size,
                              hipStream_t stream)
{
  (void)in_sizes; (void)n_in; (void)out_size;

  const float* x   = (const float*)d_in[0];
  const float* xkv = (const float*)d_in[1];
  const float* hb  = (const float*)d_in[2];   // read-only
  const float* f01 = (const float*)d_in[3];
  const float* f02 = (const float*)d_in[4];
  const float* f12 = (const float*)d_in[5];
  const float* b01 = (const float*)d_in[6];
  const float* b02 = (const float*)d_in[7];
  const float* b12 = (const float*)d_in[8];
  const float* Wq  = (const float*)d_in[9];
  const float* Wk  = (const float*)d_in[10];
  const float* Wv  = (const float*)d_in[11];
  const float* Wp  = (const float*)d_in[12];
  const float* bq  = (const float*)d_in[13];
  const float* bk  = (const float*)d_in[14];
  const float* bv  = (const float*)d_in[15];
  const float* bp  = (const float*)d_in[16];
  float* out = (float*)d_out;

  // ---- workspace layout (~104.4 MiB) ----
  char* ws = (char*)d_ws;
  u16* xb   = (u16*)(ws + 0);
  u16* xkb  = (u16*)(ws + 6774784);
  u16* wqb  = (u16*)(ws + 13549568);
  u16* wkb  = (u16*)(ws + 15646720);     // wkb/wvb contiguous -> merged KV B-matrix
  u16* wvb  = (u16*)(ws + 17743872);
  u16* wpb  = (u16*)(ws + 19841024);
  u16* Qb   = (u16*)(ws + 21938176);
  u16* Kb   = (u16*)(ws + 28712960);
  u16* Vb   = (u16*)(ws + 35487744);
  u16* Vt   = (u16*)(ws + 42262528);
  u16* ya   = (u16*)(ws + 49078272);
  float* Sreg = (float*)(ws + 55853056); // 192 x 256 x 256 fp32
  float* bT = (float*)(ws + 106184704);
  float* mm = (float*)(ws + 109330432);
  float* am = (float*)(ws + 109395968);
  const size_t need = 109461504;
  if (ws_size < need) return;

  // 1) convert inputs/weights to bf16; transpose b matrices
  cvt_all_k<<<dim3(10712), 256, 0, stream>>>(x, xkv, Wq, Wk, Wv, Wp,
                                             xb, xkb, wqb, wkb, wvb, wpb);
  btrans_k<<<dim3(4, 4, 12), 256, 0, stream>>>(b01, b02, b12, bT);
  // 2) projections (pipelined reg-prefetch GEMM); K+V merged (N=2048)
  pgemm_k<0><<<dim3(26,16),256,0,stream>>>(xb,  wqb, bq, nullptr, nullptr, Qb, nullptr, BTn, 1024);
  pgemm_k<4><<<dim3(26,32),256,0,stream>>>(xkb, wkb, bk, bv, nullptr, Kb, Vb, BTn, 2048);
  // 3) V transpose for PV B-operand
  vtrans_k<<<dim3(13,64),256,0,stream>>>(Vb, Vt);
  // 4) regional score blocks (Sreg = QK^T*SCALE + h)
  sreg_k<<<dim3(4,4,192),256,0,stream>>>(Qb, Kb, hb, Sreg);
  // 5) regional softmaxes + stats + multiplies + second softmaxes (on Sreg)
  regional_k<<<dim3(12288),256,0,stream>>>(Sreg, f01, f02, f12, bT, mm, am);
  // 6) fused flash attention -> ya
  flash_k<<<dim3(832),256,0,stream>>>(Qb, Kb, Vt, hb, Sreg, ya);
  // 7) y = y_att . Wp^T + bp -> d_out (fp32)
  pgemm_k<3><<<dim3(26,16),256,0,stream>>>(ya, wpb, bp, nullptr, out, nullptr, nullptr, BTn, 1024);
  // 8) bi_epi_ratio -> d_out tail
  ratio_k<<<dim3(4),256,0,stream>>>(mm, am, out + YSZ);
}